// Round 10
// baseline (2723.122 us; speedup 1.0000x reference)
//
#include <hip/hip_runtime.h>

// ChebNet on MI355X — Round 10: phase-synchronized persistent gathers over a
// bucket-segmented CSR (row2[j][n], 13 src-buckets of 4096 = 1MB z-slices).
// All gather blocks co-resident and sweep buckets together -> per-XCD L2
// working set ~1-2MB. (R9 failed because block generations staggered.)

constexpr int N_NODES  = 50000;
constexpr int N_EDGES  = 1600000;
constexpr int N_GRAPHS = 128;

constexpr int NB_H  = 256;                 // blocks for edge-strided kernels
constexpr int EPB   = N_EDGES / NB_H;      // 6250
constexpr int NW    = (N_NODES + 3) / 4;   // 12500 packed words (4 u8 bins)
constexpr int NBUCK = 13;                  // src bucket = s >> 12
constexpr int STRIPES = 16;                // stripes per bucket for hist/place
constexpr int R2N   = NBUCK * N_NODES;     // 650000 virtual rows

static inline int cdiv(long long a, int b) { return (int)((a + b - 1) / b); }

// ---- edge counting-sort by src bucket (R9) -----------------------------

__global__ __launch_bounds__(256) void bucket_hist_kernel(const int* __restrict__ src,
                                                          int* __restrict__ Bc) {
    __shared__ int cnt[NBUCK];
    const int b = blockIdx.x, t = threadIdx.x;
    if (t < NBUCK) cnt[t] = 0;
    __syncthreads();
    const int e0 = b * EPB, e1 = e0 + EPB;
    for (int e = e0 + t; e < e1; e += 256) atomicAdd(&cnt[src[e] >> 12], 1);
    __syncthreads();
    if (t < NBUCK) Bc[b * NBUCK + t] = cnt[t];
}

__global__ void bucket_scan_kernel(const int* __restrict__ Bc, int* __restrict__ Off,
                                   int* __restrict__ Bb) {
    __shared__ int tmp[NB_H * NBUCK];
    __shared__ int tot[NBUCK];
    __shared__ int bbase[NBUCK];
    int t = threadIdx.x;
    if (t < NBUCK) {
        int run = 0;
        for (int b = 0; b < NB_H; ++b) {
            tmp[b * NBUCK + t] = run;
            run += Bc[b * NBUCK + t];
        }
        tot[t] = run;
    }
    __syncthreads();
    if (t == 0) {
        int run = 0;
        for (int j = 0; j < NBUCK; ++j) { bbase[j] = run; run += tot[j]; }
    }
    __syncthreads();
    for (int i = t; i < NB_H * NBUCK; i += 256) {
        int j = i % NBUCK;
        Off[i] = bbase[j] + tmp[i];
    }
    if (t < NBUCK) Bb[t] = bbase[t];
    if (t == NBUCK) Bb[NBUCK] = N_EDGES;
}

__global__ __launch_bounds__(256) void bucket_scatter_kernel(const int* __restrict__ src,
                                                             const int* __restrict__ dst,
                                                             const int* __restrict__ Off,
                                                             int2* __restrict__ ebuf) {
    __shared__ int cur[NBUCK];
    const int b = blockIdx.x, t = threadIdx.x;
    if (t < NBUCK) cur[t] = 0;
    __syncthreads();
    const int e0 = b * EPB, e1 = e0 + EPB;
    const int* Ob = Off + b * NBUCK;
    for (int e = e0 + t; e < e1; e += 256) {
        int s = src[e], d = dst[e];
        int j = s >> 12;
        int r = atomicAdd(&cur[j], 1);
        ebuf[Ob[j] + r] = make_int2(s, d);
    }
}

// ---- out-degree -> dinv (on original arrays) ---------------------------

__global__ __launch_bounds__(256) void hist_src_kernel(const int* __restrict__ src,
                                                       const int* __restrict__ dst,
                                                       unsigned* __restrict__ H) {
    __shared__ unsigned lds[NW];
    const int b = blockIdx.x, t = threadIdx.x;
    for (int i = t; i < NW; i += 256) lds[i] = 0;
    __syncthreads();
    const int e0 = b * EPB, e1 = e0 + EPB;
    for (int e = e0 + t; e < e1; e += 256) {
        int s = src[e];
        if (s != dst[e]) atomicAdd(&lds[s >> 2], 1u << (8 * (s & 3)));
    }
    __syncthreads();
    unsigned* Hb = H + (size_t)b * NW;
    for (int i = t; i < NW; i += 256) Hb[i] = lds[i];
}

__global__ void merge_src_kernel(const unsigned* __restrict__ H, float* __restrict__ dinv) {
    int i = blockIdx.x * blockDim.x + threadIdx.x;
    if (i >= NW) return;
    unsigned s0 = 0, s1 = 0, s2 = 0, s3 = 0;
    for (int b = 0; b < NB_H; ++b) {
        unsigned v = H[(size_t)b * NW + i];
        s0 += v & 0xff; s1 += (v >> 8) & 0xff; s2 += (v >> 16) & 0xff; s3 += v >> 24;
    }
    dinv[4 * i + 0] = s0 ? rsqrtf((float)s0) : 0.f;
    dinv[4 * i + 1] = s1 ? rsqrtf((float)s1) : 0.f;
    dinv[4 * i + 2] = s2 ? rsqrtf((float)s2) : 0.f;
    dinv[4 * i + 3] = s3 ? rsqrtf((float)s3) : 0.f;
}

// ---- per-(bucket,stripe) dst histograms -> bucket-segmented CSR --------

__global__ __launch_bounds__(256) void histB_kernel(const int2* __restrict__ ebuf,
                                                    const int* __restrict__ Bb,
                                                    unsigned* __restrict__ Hp) {
    __shared__ unsigned lds[NW];
    const int x = blockIdx.x, j = blockIdx.y, t = threadIdx.x;
    for (int i = t; i < NW; i += 256) lds[i] = 0;
    __syncthreads();
    const int b0 = Bb[j], L = Bb[j + 1] - b0;
    const int e0 = b0 + (int)((long long)L * x / STRIPES);
    const int e1 = b0 + (int)((long long)L * (x + 1) / STRIPES);
    for (int e = e0 + t; e < e1; e += 256) {
        int2 ed = ebuf[e];
        if (ed.x != ed.y) atomicAdd(&lds[ed.y >> 2], 1u << (8 * (ed.y & 3)));
    }
    __syncthreads();
    unsigned* H = Hp + (size_t)(j * STRIPES + x) * NW;
    for (int i = t; i < NW; i += 256) H[i] = lds[i];
}

// prefix over stripes (in place -> P), totals -> cnt2[j-major]
__global__ void mergeB_kernel(unsigned* __restrict__ Hp, int* __restrict__ cnt2) {
    int tid = blockIdx.x * blockDim.x + threadIdx.x;
    if (tid >= NW * NBUCK) return;
    int j = tid / NW, i = tid % NW;
    unsigned p0 = 0, p1 = 0, p2 = 0, p3 = 0;
    size_t base = (size_t)j * STRIPES * NW + i;
    for (int x = 0; x < STRIPES; ++x) {
        size_t idx = base + (size_t)x * NW;
        unsigned v = Hp[idx];
        Hp[idx] = p0 | (p1 << 8) | (p2 << 16) | (p3 << 24);
        p0 += v & 0xff; p1 += (v >> 8) & 0xff; p2 += (v >> 16) & 0xff; p3 += v >> 24;
    }
    int nb = j * N_NODES + 4 * i;
    cnt2[nb + 0] = (int)p0; cnt2[nb + 1] = (int)p1;
    cnt2[nb + 2] = (int)p2; cnt2[nb + 3] = (int)p3;
}

// ---- 3-level scan over cnt2[650000] -> row2[650001] --------------------

constexpr int SCANA_NB = (R2N + 255) / 256;  // 2540

__global__ void scanA_kernel(const int* __restrict__ cnt, int* __restrict__ row,
                             int* __restrict__ bsum) {
    __shared__ int buf[256];
    int t = threadIdx.x;
    int i = blockIdx.x * 256 + t;
    buf[t] = (i < R2N) ? cnt[i] : 0;
    __syncthreads();
    for (int off = 1; off < 256; off <<= 1) {
        int a = (t >= off) ? buf[t - off] : 0;
        __syncthreads();
        buf[t] += a;
        __syncthreads();
    }
    if (i < R2N) row[i + 1] = buf[t];
    if (t == 255) bsum[blockIdx.x] = buf[255];
    if (i == 0) row[0] = 0;
}

__global__ void scanB_kernel(int* __restrict__ bsum) {
    __shared__ int buf[256];
    __shared__ int carry;
    int t = threadIdx.x;
    if (t == 0) carry = 0;
    __syncthreads();
    for (int base = 0; base < SCANA_NB; base += 256) {
        int i = base + t;
        int v = (i < SCANA_NB) ? bsum[i] : 0;
        buf[t] = v;
        __syncthreads();
        for (int off = 1; off < 256; off <<= 1) {
            int a = (t >= off) ? buf[t - off] : 0;
            __syncthreads();
            buf[t] += a;
            __syncthreads();
        }
        if (i < SCANA_NB) bsum[i] = carry + buf[t];
        __syncthreads();
        if (t == 255) carry += buf[255];
        __syncthreads();
    }
}

__global__ void scanC_kernel(int* __restrict__ row, const int* __restrict__ bsum) {
    int i = blockIdx.x * 256 + threadIdx.x;
    if (blockIdx.x > 0 && i < R2N) row[i + 1] += bsum[blockIdx.x - 1];
}

__global__ __launch_bounds__(256) void placeB_kernel(const int2* __restrict__ ebuf,
                                                     const int* __restrict__ Bb,
                                                     const float* __restrict__ dinv,
                                                     const int* __restrict__ row2,
                                                     const unsigned* __restrict__ P,
                                                     float2* __restrict__ csr) {
    __shared__ unsigned lds[NW];
    const int x = blockIdx.x, j = blockIdx.y, t = threadIdx.x;
    for (int i = t; i < NW; i += 256) lds[i] = 0;
    __syncthreads();
    const int b0 = Bb[j], L = Bb[j + 1] - b0;
    const int e0 = b0 + (int)((long long)L * x / STRIPES);
    const int e1 = b0 + (int)((long long)L * (x + 1) / STRIPES);
    const unsigned* Pb = P + (size_t)(j * STRIPES + x) * NW;
    const int* r = row2 + j * N_NODES;
    for (int e = e0 + t; e < e1; e += 256) {
        int2 ed = ebuf[e];
        int s = ed.x, d = ed.y;
        if (s != d) {
            float w = -dinv[s] * dinv[d];
            int sh = 8 * (d & 3);
            unsigned old = atomicAdd(&lds[d >> 2], 1u << sh);
            unsigned cur = (old >> sh) & 0xff;
            unsigned pref = (Pb[d >> 2] >> sh) & 0xff;
            int pos = r[d] + (int)pref + (int)cur;
            csr[pos] = make_float2(w, __int_as_float(s));
        }
    }
}

// ---- phase-synchronized persistent gathers -----------------------------
// All blocks co-resident; outer loop over buckets j so every wave reads the
// same 1MB z-slice at the same time. Accumulators in registers.

constexpr int G64 = 52;   // nodes/block (13 per wave), grid 962
constexpr int G32 = 56;   // nodes/block (7 per half-wave stream), grid 893

__global__ __launch_bounds__(256, 4) void gather64_phase(
        const int* __restrict__ row2, const long long* __restrict__ csr,
        const float* __restrict__ z, const float* __restrict__ prev,
        float* __restrict__ out, float alpha, float beta) {
    const int wave = threadIdx.x >> 6, lane = threadIdx.x & 63;
    const int nbase = blockIdx.x * G64;
    float acc[13];
#pragma unroll
    for (int s = 0; s < 13; ++s) acc[s] = 0.f;
    for (int j = 0; j < NBUCK; ++j) {
        const int* r = row2 + j * N_NODES;
#pragma unroll
        for (int s = 0; s < 13; ++s) {
            int node = nbase + s * 4 + wave;
            if (node < N_NODES) {
                int e0 = r[node], e1 = r[node + 1];
                float a = acc[s];
                for (int e = e0; e < e1; ++e) {
                    long long v = __builtin_nontemporal_load(csr + e);
                    float w = __int_as_float((int)(unsigned)v);
                    int sn = (int)(v >> 32);
                    a = fmaf(w, z[(size_t)sn * 64 + lane], a);
                }
                acc[s] = a;
            }
        }
    }
#pragma unroll
    for (int s = 0; s < 13; ++s) {
        int node = nbase + s * 4 + wave;
        if (node < N_NODES) {
            float r = alpha * acc[s];
            if (beta != 0.f) r = fmaf(beta, prev[(size_t)node * 64 + lane], r);
            out[(size_t)node * 64 + lane] = r;
        }
    }
}

__global__ __launch_bounds__(256, 4) void gather32_phase(
        const int* __restrict__ row2, const long long* __restrict__ csr,
        const float* __restrict__ z, const float* __restrict__ prev,
        float* __restrict__ out, float alpha, float beta) {
    const int sub = threadIdx.x >> 5, lane = threadIdx.x & 31;
    const int nbase = blockIdx.x * G32;
    float acc[7];
#pragma unroll
    for (int s = 0; s < 7; ++s) acc[s] = 0.f;
    for (int j = 0; j < NBUCK; ++j) {
        const int* r = row2 + j * N_NODES;
#pragma unroll
        for (int s = 0; s < 7; ++s) {
            int node = nbase + s * 8 + sub;
            if (node < N_NODES) {
                int e0 = r[node], e1 = r[node + 1];
                float a = acc[s];
                for (int e = e0; e < e1; ++e) {
                    long long v = __builtin_nontemporal_load(csr + e);
                    float w = __int_as_float((int)(unsigned)v);
                    int sn = (int)(v >> 32);
                    a = fmaf(w, z[(size_t)sn * 32 + lane], a);
                }
                acc[s] = a;
            }
        }
    }
#pragma unroll
    for (int s = 0; s < 7; ++s) {
        int node = nbase + s * 8 + sub;
        if (node < N_NODES) {
            float r = alpha * acc[s];
            if (beta != 0.f) r = fmaf(beta, prev[(size_t)node * 32 + lane], r);
            out[(size_t)node * 32 + lane] = r;
        }
    }
}

// F=4: z fully L2-resident; plain per-node loop over the 13 segments.
__global__ void gather4_seg(const int* __restrict__ row2, const long long* __restrict__ csr,
                            const float* __restrict__ z, const float* __restrict__ prev,
                            float* __restrict__ out, float alpha, float beta) {
    int node = blockIdx.x * blockDim.x + threadIdx.x;
    if (node >= N_NODES) return;
    const float4* z4 = (const float4*)z;
    float4 a = make_float4(0.f, 0.f, 0.f, 0.f);
    for (int j = 0; j < NBUCK; ++j) {
        int e0 = row2[j * N_NODES + node], e1 = row2[j * N_NODES + node + 1];
        for (int e = e0; e < e1; ++e) {
            long long v = __builtin_nontemporal_load(csr + e);
            float w = __int_as_float((int)(unsigned)v);
            int sn = (int)(v >> 32);
            float4 zz = z4[sn];
            a.x = fmaf(w, zz.x, a.x);
            a.y = fmaf(w, zz.y, a.y);
            a.z = fmaf(w, zz.z, a.z);
            a.w = fmaf(w, zz.w, a.w);
        }
    }
    float4 r = make_float4(alpha * a.x, alpha * a.y, alpha * a.z, alpha * a.w);
    if (beta != 0.f) {
        const float4 p = ((const float4*)prev)[node];
        r.x = fmaf(beta, p.x, r.x);
        r.y = fmaf(beta, p.y, r.y);
        r.z = fmaf(beta, p.z, r.z);
        r.w = fmaf(beta, p.w, r.w);
    }
    ((float4*)out)[node] = r;
}

// ---- combines (R5) -----------------------------------------------------

template <int FI>
__global__ __launch_bounds__(256, 4) void combine64_kernel(
        const float* __restrict__ X, const float* __restrict__ T1,
        const float* __restrict__ T2, const float* __restrict__ T3,
        const float* __restrict__ T4, const float* __restrict__ W,
        const float* __restrict__ b, float* __restrict__ out) {
    constexpr int FO = 64;
    constexpr int TS = FI + 4;
    __shared__ float Ts[64 * TS];
    __shared__ float Ws[FI * FO];
    const int t = threadIdx.x;
    const int tn = t & 15;
    const int to = t >> 4;
    const int n_base = blockIdx.x * 64;
    const float* Tk[5] = {X, T1, T2, T3, T4};

    float acc[4][4];
    {
        const float4 bb = *(const float4*)(b + 4 * to);
#pragma unroll
        for (int i = 0; i < 4; ++i) {
            acc[i][0] = bb.x; acc[i][1] = bb.y; acc[i][2] = bb.z; acc[i][3] = bb.w;
        }
    }

#pragma unroll
    for (int k = 0; k < 5; ++k) {
        __syncthreads();
        {
            const float4* s4 = (const float4*)(Tk[k] + (size_t)n_base * FI);
            constexpr int NV = 64 * FI / 4;
#pragma unroll
            for (int idx = t; idx < NV; idx += 256) {
                int r = idx / (FI / 4), c = idx % (FI / 4);
                float4 v = make_float4(0.f, 0.f, 0.f, 0.f);
                if (n_base + r < N_NODES) v = s4[idx];
                *(float4*)(Ts + r * TS + 4 * c) = v;
            }
            const float4* w4 = (const float4*)(W + (size_t)k * FI * FO);
            constexpr int WV = FI * FO / 4;
#pragma unroll
            for (int idx = t; idx < WV; idx += 256) *(float4*)(Ws + 4 * idx) = w4[idx];
        }
        __syncthreads();
#pragma unroll 4
        for (int f0 = 0; f0 < FI; f0 += 4) {
            float tv[4][4];
#pragma unroll
            for (int i = 0; i < 4; ++i) {
                float4 q = *(const float4*)(Ts + (tn + 16 * i) * TS + f0);
                tv[i][0] = q.x; tv[i][1] = q.y; tv[i][2] = q.z; tv[i][3] = q.w;
            }
#pragma unroll
            for (int j = 0; j < 4; ++j) {
                float4 w = *(const float4*)(Ws + (f0 + j) * FO + 4 * to);
#pragma unroll
                for (int i = 0; i < 4; ++i) {
                    acc[i][0] = fmaf(tv[i][j], w.x, acc[i][0]);
                    acc[i][1] = fmaf(tv[i][j], w.y, acc[i][1]);
                    acc[i][2] = fmaf(tv[i][j], w.z, acc[i][2]);
                    acc[i][3] = fmaf(tv[i][j], w.w, acc[i][3]);
                }
            }
        }
    }
    __syncthreads();
#pragma unroll
    for (int i = 0; i < 4; ++i) {
        int n = n_base + tn + 16 * i;
        if (n < N_NODES) {
            float4 r = make_float4(fmaxf(acc[i][0], 0.f), fmaxf(acc[i][1], 0.f),
                                   fmaxf(acc[i][2], 0.f), fmaxf(acc[i][3], 0.f));
            *(float4*)(out + (size_t)n * FO + 4 * to) = r;
        }
    }
}

__global__ void combine432_kernel(const float* __restrict__ X, const float* __restrict__ T1,
                                  const float* __restrict__ T2, const float* __restrict__ T3,
                                  const float* __restrict__ T4, const float* __restrict__ W,
                                  const float* __restrict__ b, float* __restrict__ out) {
    __shared__ float Ws[5 * 4 * 32];
    int t = threadIdx.x;
    for (int i = t; i < 5 * 4 * 32; i += 256) Ws[i] = W[i];
    __syncthreads();
    int node = blockIdx.x * 8 + (t >> 5);
    int o = t & 31;
    if (node >= N_NODES) return;
    const float4* Tk[5] = {(const float4*)X, (const float4*)T1, (const float4*)T2,
                           (const float4*)T3, (const float4*)T4};
    float acc = b[o];
#pragma unroll
    for (int k = 0; k < 5; ++k) {
        float4 q = Tk[k][node];
        const float* w = Ws + k * 128 + o;
        acc = fmaf(q.x, w[0], acc);
        acc = fmaf(q.y, w[32], acc);
        acc = fmaf(q.z, w[64], acc);
        acc = fmaf(q.w, w[96], acc);
    }
    out[(size_t)node * 32 + o] = fmaxf(acc, 0.f);
}

// ---- pooling + MLP -----------------------------------------------------

__global__ void pool_kernel(const float* __restrict__ h, const int* __restrict__ batch,
                            float* __restrict__ pooled, float* __restrict__ cntf) {
    int wid = blockIdx.x * (blockDim.x / 64) + (threadIdx.x >> 6);
    int lane = threadIdx.x & 63;
    int nwaves = gridDim.x * (blockDim.x / 64);
    int per = (N_NODES + nwaves - 1) / nwaves;
    int n0 = wid * per;
    int n1 = min(n0 + per, N_NODES);
    if (n0 >= n1) return;
    int cur = batch[n0];
    float acc = 0.f;
    int c = 0;
    for (int n = n0; n < n1; ++n) {
        int g = batch[n];
        if (g != cur) {
            atomicAdd(&pooled[cur * 64 + lane], acc);
            if (lane == 0) atomicAdd(&cntf[cur], (float)c);
            acc = 0.f; c = 0; cur = g;
        }
        acc += h[(size_t)n * 64 + lane];
        ++c;
    }
    atomicAdd(&pooled[cur * 64 + lane], acc);
    if (lane == 0) atomicAdd(&cntf[cur], (float)c);
}

__global__ void fc_kernel(const float* __restrict__ pooled, const float* __restrict__ cnt,
                          const float* __restrict__ w1, const float* __restrict__ b1,
                          const float* __restrict__ w2, const float* __restrict__ b2,
                          float* __restrict__ out) {
    int g = blockIdx.x;
    int t = threadIdx.x;
    __shared__ float hid[32];
    float c = fmaxf(cnt[g], 1.0f);
    float acc = b1[t];
    for (int f = 0; f < 64; ++f) acc = fmaf(pooled[g * 64 + f] / c, w1[f * 32 + t], acc);
    hid[t] = fmaxf(acc, 0.f);
    __syncthreads();
    if (t == 0) {
        float acc2 = b2[0];
        for (int o = 0; o < 32; ++o) acc2 = fmaf(hid[o], w2[o], acc2);
        out[g] = acc2;
    }
}

// ---- host orchestration ------------------------------------------------

extern "C" void kernel_launch(void* const* d_in, const int* in_sizes, int n_in,
                              void* d_out, int out_size, void* d_ws, size_t ws_size,
                              hipStream_t stream) {
    const float* x    = (const float*)d_in[0];
    const int*   ei   = (const int*)d_in[1];
    const int*   batch= (const int*)d_in[2];
    const float* W1   = (const float*)d_in[4];
    const float* b1   = (const float*)d_in[5];
    const float* W2   = (const float*)d_in[6];
    const float* b2   = (const float*)d_in[7];
    const float* W3   = (const float*)d_in[8];
    const float* b3   = (const float*)d_in[9];
    const float* fcw1 = (const float*)d_in[10];
    const float* fcb1 = (const float*)d_in[11];
    const float* fcw2 = (const float*)d_in[12];
    const float* fcb2 = (const float*)d_in[13];

    const int* src = ei;
    const int* dst = ei + N_EDGES;

    float* base = (float*)d_ws;                     // offsets in float units
    float*  dinv   = base + 0;                      // 50000
    int*    row2   = (int*)(base + 50000);          // 650001 -> pad 700016
    int*    bsum1  = (int*)(base + 700016);         // 2540 -> 702560
    int*    Bc     = (int*)(base + 702560);         // 3328 -> 705888
    int*    Off    = (int*)(base + 705888);         // 3328 -> 709216
    int*    Bb     = (int*)(base + 709216);         // 14 -> pad 709248
    float2* csr    = (float2*)(base + 709248);      // 3.2M floats -> 3909248
    float*  T1     = base + 3909248;                // 3.2M each
    float*  T2     = base + 7109248;
    float*  T3     = base + 10309248;
    float*  T4     = base + 13509248;
    float*  H1     = T4 + 1600000;                  // layer1 out (F=32)
    float*  H2     = base + 16709248;
    float*  pooled = base + 19909248;               // 8192
    float*  cntf   = base + 19917440;               // 128 -> 19917568 (~79.7MB)

    // build-phase aliases (dead until gathers / layer-2 start)
    int2*     ebuf  = (int2*)T1;      // 12.8 MB
    unsigned* Hp    = (unsigned*)T2;  // 13*16*12500 u32 = 10.4 MB
    int*      cnt2  = (int*)T3;       // 650000 ints
    unsigned* Hs    = (unsigned*)H2;  // 256*12500 u32 = 12.8 MB

    hipLaunchKernelGGL(bucket_hist_kernel, dim3(NB_H), dim3(256), 0, stream, src, Bc);
    hipLaunchKernelGGL(bucket_scan_kernel, dim3(1), dim3(256), 0, stream, Bc, Off, Bb);
    hipLaunchKernelGGL(bucket_scatter_kernel, dim3(NB_H), dim3(256), 0, stream,
                       src, dst, Off, ebuf);
    hipLaunchKernelGGL(hist_src_kernel, dim3(NB_H), dim3(256), 0, stream, src, dst, Hs);
    hipLaunchKernelGGL(merge_src_kernel, dim3(cdiv(NW, 256)), dim3(256), 0, stream, Hs, dinv);
    hipLaunchKernelGGL(histB_kernel, dim3(STRIPES, NBUCK), dim3(256), 0, stream, ebuf, Bb, Hp);
    hipLaunchKernelGGL(mergeB_kernel, dim3(cdiv(NW * NBUCK, 256)), dim3(256), 0, stream, Hp, cnt2);
    hipLaunchKernelGGL(scanA_kernel, dim3(SCANA_NB), dim3(256), 0, stream, cnt2, row2, bsum1);
    hipLaunchKernelGGL(scanB_kernel, dim3(1), dim3(256), 0, stream, bsum1);
    hipLaunchKernelGGL(scanC_kernel, dim3(SCANA_NB), dim3(256), 0, stream, row2, bsum1);
    hipLaunchKernelGGL(placeB_kernel, dim3(STRIPES, NBUCK), dim3(256), 0, stream,
                       ebuf, Bb, dinv, row2, Hp, csr);

    const long long* c8 = (const long long*)csr;

    // layer 1 (F=4 -> 32)
    {
        dim3 g(cdiv(N_NODES, 256)), blk(256);
        hipLaunchKernelGGL(gather4_seg, g, blk, 0, stream, row2, c8, x,  x,  T1, 1.f, 0.f);
        hipLaunchKernelGGL(gather4_seg, g, blk, 0, stream, row2, c8, T1, x,  T2, 2.f, -1.f);
        hipLaunchKernelGGL(gather4_seg, g, blk, 0, stream, row2, c8, T2, T1, T3, 2.f, -1.f);
        hipLaunchKernelGGL(gather4_seg, g, blk, 0, stream, row2, c8, T3, T2, T4, 2.f, -1.f);
        hipLaunchKernelGGL(combine432_kernel, dim3(cdiv(N_NODES, 8)), dim3(256), 0, stream,
                           x, T1, T2, T3, T4, W1, b1, H1);
    }
    // layer 2 (F=32 -> 64)
    {
        dim3 g(cdiv(N_NODES, G32)), blk(256);
        hipLaunchKernelGGL(gather32_phase, g, blk, 0, stream, row2, c8, H1, H1, T1, 1.f, 0.f);
        hipLaunchKernelGGL(gather32_phase, g, blk, 0, stream, row2, c8, T1, H1, T2, 2.f, -1.f);
        hipLaunchKernelGGL(gather32_phase, g, blk, 0, stream, row2, c8, T2, T1, T3, 2.f, -1.f);
        hipLaunchKernelGGL(gather32_phase, g, blk, 0, stream, row2, c8, T3, T2, T4, 2.f, -1.f);
        hipLaunchKernelGGL((combine64_kernel<32>), dim3(cdiv(N_NODES, 64)), dim3(256), 0,
                           stream, H1, T1, T2, T3, T4, W2, b2, H2);
    }
    // layer 3 (F=64 -> 64), out into T1
    {
        dim3 g(cdiv(N_NODES, G64)), blk(256);
        hipLaunchKernelGGL(gather64_phase, g, blk, 0, stream, row2, c8, H2, H2, T1, 1.f, 0.f);
        hipLaunchKernelGGL(gather64_phase, g, blk, 0, stream, row2, c8, T1, H2, T2, 2.f, -1.f);
        hipLaunchKernelGGL(gather64_phase, g, blk, 0, stream, row2, c8, T2, T1, T3, 2.f, -1.f);
        hipLaunchKernelGGL(gather64_phase, g, blk, 0, stream, row2, c8, T3, T2, T4, 2.f, -1.f);
        hipLaunchKernelGGL((combine64_kernel<64>), dim3(cdiv(N_NODES, 64)), dim3(256), 0,
                           stream, H2, T1, T2, T3, T4, W3, b3, T1);
    }

    hipMemsetAsync(pooled, 0, (8192 + 128) * sizeof(float), stream);
    hipLaunchKernelGGL(pool_kernel, dim3(128), dim3(256), 0, stream, T1, batch, pooled, cntf);
    hipLaunchKernelGGL(fc_kernel, dim3(N_GRAPHS), dim3(32), 0, stream,
                       pooled, cntf, fcw1, fcb1, fcw2, fcb2, (float*)d_out);
}